// Round 3
// baseline (298.567 us; speedup 1.0000x reference)
//
#include <hip/hip_runtime.h>
#include <math.h>

#define H 8
#define K 4
#define NN 4
#define D 256
#define NQ 1024
#define NKV 2048
#define BATCH 2
#define CH 32   // D / H

// workspace layout (bytes)
#define OFF_LOC   0u          // 65536 * float2          = 512 KB
#define OFF_ATTN  524288u     // 65536 * f32             = 256 KB
#define OFF_VWS   786432u     // 16*2048*32 f32          = 4 MB
#define OFF_HEAD  4980736u    // 2*1024*256 f32          = 2 MB
#define OFF_PD    7077888u    // 65536*16 f32 partial d  = 4 MB
#define OFF_PI    11272192u   // 65536*16 i32 partial i  = 4 MB
#define WS_NEED   15466496u

// ---------------------------------------------------------------------------
// Kernel 1: off = q@W_off + b_off (BITWISE-critical: sequential fmaf chain to
// match Eigen/oneDNN sgemm's per-element sequential-k FMA accumulation, bias
// added after) -> loc = query_pos + off   [bh][q][k] float2
//           attn = softmax_K(q@W_attn + b_attn)  [bh][q][k] float
// ---------------------------------------------------------------------------
__global__ void k_offattn(const float* __restrict__ q, const float* __restrict__ qpos,
                          const float* __restrict__ Woff, const float* __restrict__ boff,
                          const float* __restrict__ Wattn, const float* __restrict__ battn,
                          float* __restrict__ loc, float* __restrict__ attnw) {
    int row = blockIdx.x;            // b*NQ + q
    int b = row >> 10, qi = row & (NQ - 1);
    __shared__ float qs[D];
    for (int d = threadIdx.x; d < D; d += blockDim.x) qs[d] = q[(size_t)row * D + d];
    __syncthreads();
    int j = threadIdx.x;
    if (j < 64) {
        float acc = 0.0f;
        for (int d = 0; d < D; ++d) acc = fmaf(qs[d], Woff[d * 64 + j], acc);
        float off = acc + boff[j];               // bias after, like np
        int xy = j & 1;
        int hk = j >> 1;                         // h*4 + k
        int h = hk >> 2, k = hk & 3;
        float L = qpos[(size_t)row * 2 + xy] + off;
        int g = ((b * H + h) * NQ + qi) * K + k;
        loc[(size_t)g * 2 + xy] = L;
    } else if (j < 96) {
        int j2 = j - 64;                         // h*4 + k
        float acc = 0.0f;
        for (int d = 0; d < D; ++d) acc = fmaf(qs[d], Wattn[d * 32 + j2], acc);
        acc += battn[j2];
        float m = acc;
        m = fmaxf(m, __shfl_xor(m, 1));
        m = fmaxf(m, __shfl_xor(m, 2));
        float e = expf(acc - m);
        float s = e;
        s += __shfl_xor(s, 1);
        s += __shfl_xor(s, 2);
        float w = e / s;
        int h = j2 >> 2, k = j2 & 3;
        attnw[((b * H + h) * NQ + qi) * K + k] = w;
    }
}

// ---------------------------------------------------------------------------
// Kernel 2: values = kv @ W_v + b_v, stored transposed as [b*H][n_kv][32] f32.
// (2%-tolerant path; blocked accumulation fine)
// ---------------------------------------------------------------------------
__global__ void k_values(const float* __restrict__ kv, const float* __restrict__ Wv,
                         const float* __restrict__ bv, float* __restrict__ vws) {
    int r0 = blockIdx.x * 4;         // row = b*NKV + n
    __shared__ float ks[4][D];
    for (int t = threadIdx.x; t < 4 * D; t += 256) ks[t >> 8][t & 255] = kv[(size_t)r0 * D + t];
    __syncthreads();
    int c = threadIdx.x;             // h*32 + cc
    float a0 = 0.f, a1 = 0.f, a2 = 0.f, a3 = 0.f;
    for (int d = 0; d < D; ++d) {
        float w = Wv[d * D + c];
        a0 = fmaf(ks[0][d], w, a0); a1 = fmaf(ks[1][d], w, a1);
        a2 = fmaf(ks[2][d], w, a2); a3 = fmaf(ks[3][d], w, a3);
    }
    float bias = bv[c];
    a0 += bias; a1 += bias; a2 += bias; a3 += bias;
    int h = c >> 5, cc = c & 31;
    float va[4] = {a0, a1, a2, a3};
    for (int r = 0; r < 4; ++r) {
        int row = r0 + r;
        int b = row >> 11, n = row & (NKV - 1);
        vws[(((size_t)(b * H + h) * NKV) + n) * CH + cc] = va[r];
    }
}

// ---------------------------------------------------------------------------
// stable top-4 insert (strict <: earlier-fed candidate wins ties; candidates
// are fed in ascending global index => matches lax.top_k lower-index-first)
// ---------------------------------------------------------------------------
__device__ __forceinline__ void ins4(float dd, int n,
                                     float& d0, float& d1, float& d2, float& d3,
                                     int& i0, int& i1, int& i2, int& i3) {
    if (dd < d3) {
        if (dd < d2) {
            d3 = d2; i3 = i2;
            if (dd < d1) {
                d2 = d1; i2 = i1;
                if (dd < d0) { d1 = d0; i1 = i0; d0 = dd; i0 = n; }
                else         { d1 = dd; i1 = n; }
            } else { d2 = dd; i2 = n; }
        } else { d3 = dd; i3 = n; }
    }
}

// lexicographic (d, idx) insert for merging partials in arbitrary order
__device__ __forceinline__ void ins_lex(float dd, int n,
                                        float& d0, float& d1, float& d2, float& d3,
                                        int& i0, int& i1, int& i2, int& i3) {
    bool c3 = (dd < d3) || (dd == d3 && n < i3);
    if (!c3) return;
    bool c2 = (dd < d2) || (dd == d2 && n < i2);
    bool c1 = (dd < d1) || (dd == d1 && n < i1);
    bool c0 = (dd < d0) || (dd == d0 && n < i0);
    if (c2) { d3 = d2; i3 = i2;
        if (c1) { d2 = d1; i2 = i1;
            if (c0) { d1 = d0; i1 = i0; d0 = dd; i0 = n; }
            else    { d1 = dd; i1 = n; }
        } else { d2 = dd; i2 = n; }
    } else { d3 = dd; i3 = n; }
}

// ---------------------------------------------------------------------------
// Shepard weights + gather + weighted sum + head write (shared tail).
// dist replicates ref: sqrt(fl(fl(dx^2)+fl(dy^2))) + 1e-6, contract off.
// ---------------------------------------------------------------------------
__device__ __forceinline__ void knn_tail(int g, float lx, float ly,
                                         int i0, int i1, int i2, int i3,
                                         const float* __restrict__ kvpos,
                                         const float* __restrict__ attnw,
                                         const float* __restrict__ vws,
                                         float power, float* __restrict__ head) {
    #pragma clang fp contract(off)
    int bh = g >> 12;
    int b = bh >> 3, h = bh & 7;
    int qi = (g >> 2) & (NQ - 1);
    int k = g & 3;
    int idx[4] = {i0, i1, i2, i3};
    float z[4];
    #pragma unroll
    for (int u = 0; u < 4; ++u) {
        float kx = kvpos[(size_t)(b * NKV + idx[u]) * 2 + 0];
        float ky = kvpos[(size_t)(b * NKV + idx[u]) * 2 + 1];
        float dx = kx - lx;
        float dy = ky - ly;
        float dist = sqrtf(dx * dx + dy * dy) + 1e-6f;
        z[u] = -power * dist;
    }
    float m = fmaxf(fmaxf(z[0], z[1]), fmaxf(z[2], z[3]));
    float e0 = expf(z[0] - m), e1 = expf(z[1] - m), e2 = expf(z[2] - m), e3 = expf(z[3] - m);
    float esum = e0 + e1 + e2 + e3;
    float w0 = e0 / esum, w1 = e1 / esum, w2 = e2 / esum, w3 = e3 / esum;

    const float4* vp0 = (const float4*)(vws + ((size_t)bh * NKV + i0) * CH);
    const float4* vp1 = (const float4*)(vws + ((size_t)bh * NKV + i1) * CH);
    const float4* vp2 = (const float4*)(vws + ((size_t)bh * NKV + i2) * CH);
    const float4* vp3 = (const float4*)(vws + ((size_t)bh * NKV + i3) * CH);
    float a = attnw[g];
    float4 acc[8];
    #pragma unroll
    for (int t = 0; t < 8; ++t) {
        float4 x0 = vp0[t], x1 = vp1[t], x2 = vp2[t], x3 = vp3[t];
        float4 r;
        r.x = a * (w0 * x0.x + w1 * x1.x + w2 * x2.x + w3 * x3.x);
        r.y = a * (w0 * x0.y + w1 * x1.y + w2 * x2.y + w3 * x3.y);
        r.z = a * (w0 * x0.z + w1 * x1.z + w2 * x2.z + w3 * x3.z);
        r.w = a * (w0 * x0.w + w1 * x1.w + w2 * x2.w + w3 * x3.w);
        r.x += __shfl_xor(r.x, 1); r.x += __shfl_xor(r.x, 2);
        r.y += __shfl_xor(r.y, 1); r.y += __shfl_xor(r.y, 2);
        r.z += __shfl_xor(r.z, 1); r.z += __shfl_xor(r.z, 2);
        r.w += __shfl_xor(r.w, 1); r.w += __shfl_xor(r.w, 2);
        acc[t] = r;
    }
    float4* hp = (float4*)(head + ((size_t)(b * NQ + qi)) * D + h * CH);
    hp[k * 2]     = acc[k * 2];
    hp[k * 2 + 1] = acc[k * 2 + 1];
}

// ---------------------------------------------------------------------------
// Kernel 3a: split-K top-4 scan. Each block: 256 points x 512 candidates.
// d2 replicates XLA-CPU (Eigen/oneDNN) BITWISE: the k=2 contraction is an
// ascending-k FMA chain: dot = fma(ly,ky, fl(lx*kx)); then
// t = fl(S + (-2*dot)) == fl(S - fl(2*dot))  (pow-2 scaling exact, commutes
// through fma/add rounding).  contract off elsewhere.
// ---------------------------------------------------------------------------
__global__ void k_knn_part(const float* __restrict__ kvpos, const float* __restrict__ loc,
                           float* __restrict__ part_d, int* __restrict__ part_i) {
    #pragma clang fp contract(off)
    int group = blockIdx.x >> 2;
    int slice = blockIdx.x & 3;
    int g = group * 256 + threadIdx.x;        // point id, uniform bh per block
    int bh = g >> 12;
    int b = bh >> 3;
    int n0 = slice * (NKV / 4);

    __shared__ float4 kvs[NKV / 4];
    for (int i = threadIdx.x; i < NKV / 4; i += 256) {
        int n = n0 + i;
        float x = kvpos[(size_t)(b * NKV + n) * 2 + 0];
        float y = kvpos[(size_t)(b * NKV + n) * 2 + 1];
        kvs[i] = make_float4(-2.0f * x, -2.0f * y, x * x + y * y, 0.0f);
    }
    __syncthreads();

    const float2* lp = (const float2*)loc;
    float2 L = lp[g];
    float lx = L.x, ly = L.y;
    float sl = lx * lx + ly * ly;

    float d0 = 1e30f, d1 = 1e30f, d2 = 1e30f, d3 = 1e30f;
    int i0 = 0, i1 = 0, i2 = 0, i3 = 0;
    for (int i = 0; i < NKV / 4; i += 4) {
        float4 c0 = kvs[i], c1 = kvs[i + 1], c2 = kvs[i + 2], c3 = kvs[i + 3];
        float t0 = (sl + c0.z) + fmaf(ly, c0.y, lx * c0.x);
        float t1 = (sl + c1.z) + fmaf(ly, c1.y, lx * c1.x);
        float t2 = (sl + c2.z) + fmaf(ly, c2.y, lx * c2.x);
        float t3 = (sl + c3.z) + fmaf(ly, c3.y, lx * c3.x);
        float mn = fminf(fminf(t0, t1), fminf(t2, t3));
        if (mn < d3) {
            ins4(t0, n0 + i,     d0, d1, d2, d3, i0, i1, i2, i3);
            ins4(t1, n0 + i + 1, d0, d1, d2, d3, i0, i1, i2, i3);
            ins4(t2, n0 + i + 2, d0, d1, d2, d3, i0, i1, i2, i3);
            ins4(t3, n0 + i + 3, d0, d1, d2, d3, i0, i1, i2, i3);
        }
    }
    size_t base = (size_t)g * 16 + slice * 4;
    part_d[base + 0] = d0; part_d[base + 1] = d1; part_d[base + 2] = d2; part_d[base + 3] = d3;
    part_i[base + 0] = i0; part_i[base + 1] = i1; part_i[base + 2] = i2; part_i[base + 3] = i3;
}

// Kernel 3b: merge 4 partial top-4 lists (lexicographic => stable) + tail
__global__ void k_knn_merge(const float* __restrict__ kvpos, const float* __restrict__ loc,
                            const float* __restrict__ attnw, const float* __restrict__ vws,
                            const float* __restrict__ sp,
                            const float* __restrict__ part_d, const int* __restrict__ part_i,
                            float* __restrict__ head) {
    #pragma clang fp contract(off)
    int g = blockIdx.x * 256 + threadIdx.x;
    float d0 = 1e30f, d1 = 1e30f, d2 = 1e30f, d3 = 1e30f;
    int i0 = 0x7FFFFFFF, i1 = 0x7FFFFFFF, i2 = 0x7FFFFFFF, i3 = 0x7FFFFFFF;
    #pragma unroll
    for (int s = 0; s < 4; ++s) {
        size_t base = (size_t)g * 16 + s * 4;
        #pragma unroll
        for (int r = 0; r < 4; ++r) {
            ins_lex(part_d[base + r], part_i[base + r], d0, d1, d2, d3, i0, i1, i2, i3);
        }
    }
    const float2* lp = (const float2*)loc;
    float2 L = lp[g];
    float power = fmaxf(sp[0], 0.0f) + 1e-6f;
    knn_tail(g, L.x, L.y, i0, i1, i2, i3, kvpos, attnw, vws, power, head);
}

// Kernel 3 (fallback, if ws too small for partials): fused full scan
__global__ void k_knn_fused(const float* __restrict__ kvpos, const float* __restrict__ loc,
                            const float* __restrict__ attnw, const float* __restrict__ vws,
                            const float* __restrict__ sp, float* __restrict__ head) {
    #pragma clang fp contract(off)
    int g = blockIdx.x * 256 + threadIdx.x;
    int bh = g >> 12;
    int b = bh >> 3;
    __shared__ float4 kvs[NKV];
    for (int n = threadIdx.x; n < NKV; n += 256) {
        float x = kvpos[(size_t)(b * NKV + n) * 2 + 0];
        float y = kvpos[(size_t)(b * NKV + n) * 2 + 1];
        kvs[n] = make_float4(-2.0f * x, -2.0f * y, x * x + y * y, 0.0f);
    }
    __syncthreads();
    const float2* lp = (const float2*)loc;
    float2 L = lp[g];
    float lx = L.x, ly = L.y;
    float sl = lx * lx + ly * ly;
    float d0 = 1e30f, d1 = 1e30f, d2 = 1e30f, d3 = 1e30f;
    int i0 = 0, i1 = 0, i2 = 0, i3 = 0;
    for (int n = 0; n < NKV; n += 4) {
        float4 c0 = kvs[n], c1 = kvs[n + 1], c2 = kvs[n + 2], c3 = kvs[n + 3];
        float t0 = (sl + c0.z) + fmaf(ly, c0.y, lx * c0.x);
        float t1 = (sl + c1.z) + fmaf(ly, c1.y, lx * c1.x);
        float t2 = (sl + c2.z) + fmaf(ly, c2.y, lx * c2.x);
        float t3 = (sl + c3.z) + fmaf(ly, c3.y, lx * c3.x);
        float mn = fminf(fminf(t0, t1), fminf(t2, t3));
        if (mn < d3) {
            ins4(t0, n,     d0, d1, d2, d3, i0, i1, i2, i3);
            ins4(t1, n + 1, d0, d1, d2, d3, i0, i1, i2, i3);
            ins4(t2, n + 2, d0, d1, d2, d3, i0, i1, i2, i3);
            ins4(t3, n + 3, d0, d1, d2, d3, i0, i1, i2, i3);
        }
    }
    float power = fmaxf(sp[0], 0.0f) + 1e-6f;
    knn_tail(g, lx, ly, i0, i1, i2, i3, kvpos, attnw, vws, power, head);
}

// ---------------------------------------------------------------------------
// Kernel 4: out = head @ W_out + b_out  (f32 store)
// ---------------------------------------------------------------------------
__global__ void k_out(const float* __restrict__ head, const float* __restrict__ Wout,
                      const float* __restrict__ bout, float* __restrict__ out) {
    int r0 = blockIdx.x * 4;
    __shared__ float hs[4][D];
    for (int t = threadIdx.x; t < 4 * D; t += 256) hs[t >> 8][t & 255] = head[(size_t)r0 * D + t];
    __syncthreads();
    int c = threadIdx.x;
    float a0 = 0.f, a1 = 0.f, a2 = 0.f, a3 = 0.f;
    for (int d = 0; d < D; ++d) {
        float w = Wout[d * D + c];
        a0 = fmaf(hs[0][d], w, a0); a1 = fmaf(hs[1][d], w, a1);
        a2 = fmaf(hs[2][d], w, a2); a3 = fmaf(hs[3][d], w, a3);
    }
    float bias = bout[c];
    out[(size_t)(r0 + 0) * D + c] = a0 + bias;
    out[(size_t)(r0 + 1) * D + c] = a1 + bias;
    out[(size_t)(r0 + 2) * D + c] = a2 + bias;
    out[(size_t)(r0 + 3) * D + c] = a3 + bias;
}

// ---------------------------------------------------------------------------
extern "C" void kernel_launch(void* const* d_in, const int* in_sizes, int n_in,
                              void* d_out, int out_size, void* d_ws, size_t ws_size,
                              hipStream_t stream) {
    (void)in_sizes; (void)n_in; (void)out_size;
    const float* q     = (const float*)d_in[0];
    const float* qpos  = (const float*)d_in[1];
    const float* kv    = (const float*)d_in[2];
    const float* kvp   = (const float*)d_in[3];
    const float* Woff  = (const float*)d_in[4];
    const float* boff  = (const float*)d_in[5];
    const float* Wattn = (const float*)d_in[6];
    const float* battn = (const float*)d_in[7];
    const float* Wv    = (const float*)d_in[8];
    const float* bv    = (const float*)d_in[9];
    const float* Wout  = (const float*)d_in[10];
    const float* bout  = (const float*)d_in[11];
    const float* sp    = (const float*)d_in[12];
    float* out = (float*)d_out;

    char* ws = (char*)d_ws;
    float* loc    = (float*)(ws + OFF_LOC);
    float* attnw  = (float*)(ws + OFF_ATTN);
    float* vws    = (float*)(ws + OFF_VWS);
    float* head   = (float*)(ws + OFF_HEAD);
    float* part_d = (float*)(ws + OFF_PD);
    int*   part_i = (int*)(ws + OFF_PI);

    hipLaunchKernelGGL(k_offattn, dim3(BATCH * NQ), dim3(128), 0, stream,
                       q, qpos, Woff, boff, Wattn, battn, loc, attnw);
    hipLaunchKernelGGL(k_values, dim3(BATCH * NKV / 4), dim3(256), 0, stream,
                       kv, Wv, bv, vws);
    if (ws_size >= (size_t)WS_NEED) {
        hipLaunchKernelGGL(k_knn_part, dim3(BATCH * H * NQ * K / 256 * 4), dim3(256), 0, stream,
                           kvp, loc, part_d, part_i);
        hipLaunchKernelGGL(k_knn_merge, dim3(BATCH * H * NQ * K / 256), dim3(256), 0, stream,
                           kvp, loc, attnw, vws, sp, part_d, part_i, head);
    } else {
        hipLaunchKernelGGL(k_knn_fused, dim3(BATCH * H * NQ * K / 256), dim3(256), 0, stream,
                           kvp, loc, attnw, vws, sp, head);
    }
    hipLaunchKernelGGL(k_out, dim3(BATCH * NQ / 4), dim3(256), 0, stream,
                       head, Wout, bout, out);
}

// Round 4
// 166.133 us; speedup vs baseline: 1.7972x; 1.7972x over previous
//
#include <hip/hip_runtime.h>
#include <math.h>

#define H 8
#define K 4
#define NN 4
#define D 256
#define NQ 1024
#define NKV 2048
#define BATCH 2
#define CH 32   // D / H

// workspace layout (bytes) — unchanged from round 3
#define OFF_LOC   0u          // 65536 * float2          = 512 KB
#define OFF_ATTN  524288u     // 65536 * f32             = 256 KB
#define OFF_VWS   786432u     // 16*2048*32 f32          = 4 MB
#define OFF_HEAD  4980736u    // 2*1024*256 f32          = 2 MB
#define OFF_PD    7077888u    // 65536*16 f32 partial d  = 4 MB
#define OFF_PI    11272192u   // 65536*16 i32 partial i  = 4 MB
#define WS_NEED   15466496u

// ---------------------------------------------------------------------------
// Kernel 1: off = q@W_off + b_off (sequential fmaf chain = Eigen/oneDNN sgemm
// semantics, bias after) -> loc; attn = softmax_K(q@W_attn + b_attn)
// ---------------------------------------------------------------------------
__global__ void k_offattn(const float* __restrict__ q, const float* __restrict__ qpos,
                          const float* __restrict__ Woff, const float* __restrict__ boff,
                          const float* __restrict__ Wattn, const float* __restrict__ battn,
                          float* __restrict__ loc, float* __restrict__ attnw) {
    int row = blockIdx.x;            // b*NQ + q
    int b = row >> 10, qi = row & (NQ - 1);
    __shared__ float qs[D];
    for (int d = threadIdx.x; d < D; d += blockDim.x) qs[d] = q[(size_t)row * D + d];
    __syncthreads();
    int j = threadIdx.x;
    if (j < 64) {
        float acc = 0.0f;
        for (int d = 0; d < D; ++d) acc = fmaf(qs[d], Woff[d * 64 + j], acc);
        float off = acc + boff[j];               // bias after, like np
        int xy = j & 1;
        int hk = j >> 1;                         // h*4 + k
        int h = hk >> 2, k = hk & 3;
        float L = qpos[(size_t)row * 2 + xy] + off;
        int g = ((b * H + h) * NQ + qi) * K + k;
        loc[(size_t)g * 2 + xy] = L;
    } else if (j < 96) {
        int j2 = j - 64;                         // h*4 + k
        float acc = 0.0f;
        for (int d = 0; d < D; ++d) acc = fmaf(qs[d], Wattn[d * 32 + j2], acc);
        acc += battn[j2];
        float m = acc;
        m = fmaxf(m, __shfl_xor(m, 1));
        m = fmaxf(m, __shfl_xor(m, 2));
        float e = expf(acc - m);
        float s = e;
        s += __shfl_xor(s, 1);
        s += __shfl_xor(s, 2);
        float w = e / s;
        int h = j2 >> 2, k = j2 & 3;
        attnw[((b * H + h) * NQ + qi) * K + k] = w;
    }
}

// ---------------------------------------------------------------------------
// Kernel 2: values = kv @ W_v + b_v, stored transposed as [b*H][n_kv][32] f32.
// ---------------------------------------------------------------------------
__global__ void k_values(const float* __restrict__ kv, const float* __restrict__ Wv,
                         const float* __restrict__ bv, float* __restrict__ vws) {
    int r0 = blockIdx.x * 4;         // row = b*NKV + n
    __shared__ float ks[4][D];
    for (int t = threadIdx.x; t < 4 * D; t += 256) ks[t >> 8][t & 255] = kv[(size_t)r0 * D + t];
    __syncthreads();
    int c = threadIdx.x;             // h*32 + cc
    float a0 = 0.f, a1 = 0.f, a2 = 0.f, a3 = 0.f;
    for (int d = 0; d < D; ++d) {
        float w = Wv[d * D + c];
        a0 = fmaf(ks[0][d], w, a0); a1 = fmaf(ks[1][d], w, a1);
        a2 = fmaf(ks[2][d], w, a2); a3 = fmaf(ks[3][d], w, a3);
    }
    float bias = bv[c];
    a0 += bias; a1 += bias; a2 += bias; a3 += bias;
    int h = c >> 5, cc = c & 31;
    float va[4] = {a0, a1, a2, a3};
    for (int r = 0; r < 4; ++r) {
        int row = r0 + r;
        int b = row >> 11, n = row & (NKV - 1);
        vws[(((size_t)(b * H + h) * NKV) + n) * CH + cc] = va[r];
    }
}

// ---------------------------------------------------------------------------
// BRANCHLESS stable top-4 insert: strict < (incumbent wins ties; ascending
// feed => lower index first, matches lax.top_k). Pure v_cmp/v_cndmask, no
// divergence. Slot updates top-down so old lower slots shift correctly.
// ---------------------------------------------------------------------------
__device__ __forceinline__ void bins4(float t, int n,
                                      float& d0, float& d1, float& d2, float& d3,
                                      int& i0, int& i1, int& i2, int& i3) {
    bool c0 = t < d0, c1 = t < d1, c2 = t < d2, c3 = t < d3;
    d3 = c3 ? (c2 ? d2 : t) : d3;
    i3 = c3 ? (c2 ? i2 : n) : i3;
    d2 = c2 ? (c1 ? d1 : t) : d2;
    i2 = c2 ? (c1 ? i1 : n) : i2;
    d1 = c1 ? (c0 ? d0 : t) : d1;
    i1 = c1 ? (c0 ? i0 : n) : i1;
    d0 = c0 ? t : d0;
    i0 = c0 ? n : i0;
}

// lexicographic (d, idx) insert for merging partials in arbitrary order
__device__ __forceinline__ void ins_lex(float dd, int n,
                                        float& d0, float& d1, float& d2, float& d3,
                                        int& i0, int& i1, int& i2, int& i3) {
    bool c3 = (dd < d3) || (dd == d3 && n < i3);
    if (!c3) return;
    bool c2 = (dd < d2) || (dd == d2 && n < i2);
    bool c1 = (dd < d1) || (dd == d1 && n < i1);
    bool c0 = (dd < d0) || (dd == d0 && n < i0);
    if (c2) { d3 = d2; i3 = i2;
        if (c1) { d2 = d1; i2 = i1;
            if (c0) { d1 = d0; i1 = i0; d0 = dd; i0 = n; }
            else    { d1 = dd; i1 = n; }
        } else { d2 = dd; i2 = n; }
    } else { d3 = dd; i3 = n; }
}

// ---------------------------------------------------------------------------
// Shepard weights + gather + weighted sum + head write (shared tail).
// ---------------------------------------------------------------------------
__device__ __forceinline__ void knn_tail(int g, float lx, float ly,
                                         int i0, int i1, int i2, int i3,
                                         const float* __restrict__ kvpos,
                                         const float* __restrict__ attnw,
                                         const float* __restrict__ vws,
                                         float power, float* __restrict__ head) {
    #pragma clang fp contract(off)
    int bh = g >> 12;
    int b = bh >> 3, h = bh & 7;
    int qi = (g >> 2) & (NQ - 1);
    int k = g & 3;
    int idx[4] = {i0, i1, i2, i3};
    float z[4];
    #pragma unroll
    for (int u = 0; u < 4; ++u) {
        float kx = kvpos[(size_t)(b * NKV + idx[u]) * 2 + 0];
        float ky = kvpos[(size_t)(b * NKV + idx[u]) * 2 + 1];
        float dx = kx - lx;
        float dy = ky - ly;
        float dist = sqrtf(dx * dx + dy * dy) + 1e-6f;
        z[u] = -power * dist;
    }
    float m = fmaxf(fmaxf(z[0], z[1]), fmaxf(z[2], z[3]));
    float e0 = expf(z[0] - m), e1 = expf(z[1] - m), e2 = expf(z[2] - m), e3 = expf(z[3] - m);
    float esum = e0 + e1 + e2 + e3;
    float w0 = e0 / esum, w1 = e1 / esum, w2 = e2 / esum, w3 = e3 / esum;

    const float4* vp0 = (const float4*)(vws + ((size_t)bh * NKV + i0) * CH);
    const float4* vp1 = (const float4*)(vws + ((size_t)bh * NKV + i1) * CH);
    const float4* vp2 = (const float4*)(vws + ((size_t)bh * NKV + i2) * CH);
    const float4* vp3 = (const float4*)(vws + ((size_t)bh * NKV + i3) * CH);
    float a = attnw[g];
    float4 acc[8];
    #pragma unroll
    for (int t = 0; t < 8; ++t) {
        float4 x0 = vp0[t], x1 = vp1[t], x2 = vp2[t], x3 = vp3[t];
        float4 r;
        r.x = a * (w0 * x0.x + w1 * x1.x + w2 * x2.x + w3 * x3.x);
        r.y = a * (w0 * x0.y + w1 * x1.y + w2 * x2.y + w3 * x3.y);
        r.z = a * (w0 * x0.z + w1 * x1.z + w2 * x2.z + w3 * x3.z);
        r.w = a * (w0 * x0.w + w1 * x1.w + w2 * x2.w + w3 * x3.w);
        r.x += __shfl_xor(r.x, 1); r.x += __shfl_xor(r.x, 2);
        r.y += __shfl_xor(r.y, 1); r.y += __shfl_xor(r.y, 2);
        r.z += __shfl_xor(r.z, 1); r.z += __shfl_xor(r.z, 2);
        r.w += __shfl_xor(r.w, 1); r.w += __shfl_xor(r.w, 2);
        acc[t] = r;
    }
    float4* hp = (float4*)(head + ((size_t)(b * NQ + qi)) * D + h * CH);
    hp[k * 2]     = acc[k * 2];
    hp[k * 2 + 1] = acc[k * 2 + 1];
}

// ---------------------------------------------------------------------------
// Kernel 3a: split-K top-4 scan, BRANCHLESS inner loop, SoA LDS.
// d2 bitwise-identical to round 3: t = fl(fl(sl+skv) + fma(ly,-2ky, fl(lx*-2kx)))
// ---------------------------------------------------------------------------
__global__ void k_knn_part(const float* __restrict__ kvpos, const float* __restrict__ loc,
                           float* __restrict__ part_d, int* __restrict__ part_i) {
    #pragma clang fp contract(off)
    int group = blockIdx.x >> 2;
    int slice = blockIdx.x & 3;
    int g = group * 256 + threadIdx.x;        // point id, uniform bh per block
    int bh = g >> 12;
    int b = bh >> 3;
    int n0 = slice * (NKV / 4);

    __shared__ float sx[NKV / 4];
    __shared__ float sy[NKV / 4];
    __shared__ float sz[NKV / 4];
    for (int i = threadIdx.x; i < NKV / 4; i += 256) {
        int n = n0 + i;
        float x = kvpos[(size_t)(b * NKV + n) * 2 + 0];
        float y = kvpos[(size_t)(b * NKV + n) * 2 + 1];
        sx[i] = -2.0f * x;
        sy[i] = -2.0f * y;
        sz[i] = x * x + y * y;
    }
    __syncthreads();

    const float2* lp = (const float2*)loc;
    float2 L = lp[g];
    float lx = L.x, ly = L.y;
    float sl = lx * lx + ly * ly;

    const float4* x4 = (const float4*)sx;
    const float4* y4 = (const float4*)sy;
    const float4* z4 = (const float4*)sz;

    float d0 = 1e30f, d1 = 1e30f, d2 = 1e30f, d3 = 1e30f;
    int i0 = 0, i1 = 0, i2 = 0, i3 = 0;
    for (int i = 0; i < NKV / 4; i += 8) {
        int v = i >> 2;
        float4 xA = x4[v], xB = x4[v + 1];
        float4 yA = y4[v], yB = y4[v + 1];
        float4 zA = z4[v], zB = z4[v + 1];
        float t0 = (sl + zA.x) + fmaf(ly, yA.x, lx * xA.x);
        float t1 = (sl + zA.y) + fmaf(ly, yA.y, lx * xA.y);
        float t2 = (sl + zA.z) + fmaf(ly, yA.z, lx * xA.z);
        float t3 = (sl + zA.w) + fmaf(ly, yA.w, lx * xA.w);
        float t4 = (sl + zB.x) + fmaf(ly, yB.x, lx * xB.x);
        float t5 = (sl + zB.y) + fmaf(ly, yB.y, lx * xB.y);
        float t6 = (sl + zB.z) + fmaf(ly, yB.z, lx * xB.z);
        float t7 = (sl + zB.w) + fmaf(ly, yB.w, lx * xB.w);
        int n = n0 + i;
        bins4(t0, n + 0, d0, d1, d2, d3, i0, i1, i2, i3);
        bins4(t1, n + 1, d0, d1, d2, d3, i0, i1, i2, i3);
        bins4(t2, n + 2, d0, d1, d2, d3, i0, i1, i2, i3);
        bins4(t3, n + 3, d0, d1, d2, d3, i0, i1, i2, i3);
        bins4(t4, n + 4, d0, d1, d2, d3, i0, i1, i2, i3);
        bins4(t5, n + 5, d0, d1, d2, d3, i0, i1, i2, i3);
        bins4(t6, n + 6, d0, d1, d2, d3, i0, i1, i2, i3);
        bins4(t7, n + 7, d0, d1, d2, d3, i0, i1, i2, i3);
    }
    size_t base = (size_t)g * 16 + slice * 4;
    part_d[base + 0] = d0; part_d[base + 1] = d1; part_d[base + 2] = d2; part_d[base + 3] = d3;
    part_i[base + 0] = i0; part_i[base + 1] = i1; part_i[base + 2] = i2; part_i[base + 3] = i3;
}

// Kernel 3b: merge 4 partial top-4 lists (lexicographic => stable) + tail
__global__ void k_knn_merge(const float* __restrict__ kvpos, const float* __restrict__ loc,
                            const float* __restrict__ attnw, const float* __restrict__ vws,
                            const float* __restrict__ sp,
                            const float* __restrict__ part_d, const int* __restrict__ part_i,
                            float* __restrict__ head) {
    #pragma clang fp contract(off)
    int g = blockIdx.x * 256 + threadIdx.x;
    float d0 = 1e30f, d1 = 1e30f, d2 = 1e30f, d3 = 1e30f;
    int i0 = 0x7FFFFFFF, i1 = 0x7FFFFFFF, i2 = 0x7FFFFFFF, i3 = 0x7FFFFFFF;
    #pragma unroll
    for (int s = 0; s < 4; ++s) {
        size_t base = (size_t)g * 16 + s * 4;
        #pragma unroll
        for (int r = 0; r < 4; ++r) {
            ins_lex(part_d[base + r], part_i[base + r], d0, d1, d2, d3, i0, i1, i2, i3);
        }
    }
    const float2* lp = (const float2*)loc;
    float2 L = lp[g];
    float power = fmaxf(sp[0], 0.0f) + 1e-6f;
    knn_tail(g, L.x, L.y, i0, i1, i2, i3, kvpos, attnw, vws, power, head);
}

// Kernel 3 (fallback, if ws too small for partials): fused full scan, branchless
__global__ void k_knn_fused(const float* __restrict__ kvpos, const float* __restrict__ loc,
                            const float* __restrict__ attnw, const float* __restrict__ vws,
                            const float* __restrict__ sp, float* __restrict__ head) {
    #pragma clang fp contract(off)
    int g = blockIdx.x * 256 + threadIdx.x;
    int bh = g >> 12;
    int b = bh >> 3;
    __shared__ float sx[NKV];
    __shared__ float sy[NKV];
    __shared__ float sz[NKV];
    for (int n = threadIdx.x; n < NKV; n += 256) {
        float x = kvpos[(size_t)(b * NKV + n) * 2 + 0];
        float y = kvpos[(size_t)(b * NKV + n) * 2 + 1];
        sx[n] = -2.0f * x;
        sy[n] = -2.0f * y;
        sz[n] = x * x + y * y;
    }
    __syncthreads();
    const float2* lp = (const float2*)loc;
    float2 L = lp[g];
    float lx = L.x, ly = L.y;
    float sl = lx * lx + ly * ly;
    const float4* x4 = (const float4*)sx;
    const float4* y4 = (const float4*)sy;
    const float4* z4 = (const float4*)sz;
    float d0 = 1e30f, d1 = 1e30f, d2 = 1e30f, d3 = 1e30f;
    int i0 = 0, i1 = 0, i2 = 0, i3 = 0;
    for (int n = 0; n < NKV; n += 4) {
        int v = n >> 2;
        float4 xA = x4[v], yA = y4[v], zA = z4[v];
        float t0 = (sl + zA.x) + fmaf(ly, yA.x, lx * xA.x);
        float t1 = (sl + zA.y) + fmaf(ly, yA.y, lx * xA.y);
        float t2 = (sl + zA.z) + fmaf(ly, yA.z, lx * xA.z);
        float t3 = (sl + zA.w) + fmaf(ly, yA.w, lx * xA.w);
        bins4(t0, n + 0, d0, d1, d2, d3, i0, i1, i2, i3);
        bins4(t1, n + 1, d0, d1, d2, d3, i0, i1, i2, i3);
        bins4(t2, n + 2, d0, d1, d2, d3, i0, i1, i2, i3);
        bins4(t3, n + 3, d0, d1, d2, d3, i0, i1, i2, i3);
    }
    float power = fmaxf(sp[0], 0.0f) + 1e-6f;
    knn_tail(g, lx, ly, i0, i1, i2, i3, kvpos, attnw, vws, power, head);
}

// ---------------------------------------------------------------------------
// Kernel 4: out = head @ W_out + b_out  (f32 store)
// ---------------------------------------------------------------------------
__global__ void k_out(const float* __restrict__ head, const float* __restrict__ Wout,
                      const float* __restrict__ bout, float* __restrict__ out) {
    int r0 = blockIdx.x * 4;
    __shared__ float hs[4][D];
    for (int t = threadIdx.x; t < 4 * D; t += 256) hs[t >> 8][t & 255] = head[(size_t)r0 * D + t];
    __syncthreads();
    int c = threadIdx.x;
    float a0 = 0.f, a1 = 0.f, a2 = 0.f, a3 = 0.f;
    for (int d = 0; d < D; ++d) {
        float w = Wout[d * D + c];
        a0 = fmaf(hs[0][d], w, a0); a1 = fmaf(hs[1][d], w, a1);
        a2 = fmaf(hs[2][d], w, a2); a3 = fmaf(hs[3][d], w, a3);
    }
    float bias = bout[c];
    out[(size_t)(r0 + 0) * D + c] = a0 + bias;
    out[(size_t)(r0 + 1) * D + c] = a1 + bias;
    out[(size_t)(r0 + 2) * D + c] = a2 + bias;
    out[(size_t)(r0 + 3) * D + c] = a3 + bias;
}

// ---------------------------------------------------------------------------
extern "C" void kernel_launch(void* const* d_in, const int* in_sizes, int n_in,
                              void* d_out, int out_size, void* d_ws, size_t ws_size,
                              hipStream_t stream) {
    (void)in_sizes; (void)n_in; (void)out_size;
    const float* q     = (const float*)d_in[0];
    const float* qpos  = (const float*)d_in[1];
    const float* kv    = (const float*)d_in[2];
    const float* kvp   = (const float*)d_in[3];
    const float* Woff  = (const float*)d_in[4];
    const float* boff  = (const float*)d_in[5];
    const float* Wattn = (const float*)d_in[6];
    const float* battn = (const float*)d_in[7];
    const float* Wv    = (const float*)d_in[8];
    const float* bv    = (const float*)d_in[9];
    const float* Wout  = (const float*)d_in[10];
    const float* bout  = (const float*)d_in[11];
    const float* sp    = (const float*)d_in[12];
    float* out = (float*)d_out;

    char* ws = (char*)d_ws;
    float* loc    = (float*)(ws + OFF_LOC);
    float* attnw  = (float*)(ws + OFF_ATTN);
    float* vws    = (float*)(ws + OFF_VWS);
    float* head   = (float*)(ws + OFF_HEAD);
    float* part_d = (float*)(ws + OFF_PD);
    int*   part_i = (int*)(ws + OFF_PI);

    hipLaunchKernelGGL(k_offattn, dim3(BATCH * NQ), dim3(128), 0, stream,
                       q, qpos, Woff, boff, Wattn, battn, loc, attnw);
    hipLaunchKernelGGL(k_values, dim3(BATCH * NKV / 4), dim3(256), 0, stream,
                       kv, Wv, bv, vws);
    if (ws_size >= (size_t)WS_NEED) {
        hipLaunchKernelGGL(k_knn_part, dim3(BATCH * H * NQ * K / 256 * 4), dim3(256), 0, stream,
                           kvp, loc, part_d, part_i);
        hipLaunchKernelGGL(k_knn_merge, dim3(BATCH * H * NQ * K / 256), dim3(256), 0, stream,
                           kvp, loc, attnw, vws, sp, part_d, part_i, head);
    } else {
        hipLaunchKernelGGL(k_knn_fused, dim3(BATCH * H * NQ * K / 256), dim3(256), 0, stream,
                           kvp, loc, attnw, vws, sp, head);
    }
    hipLaunchKernelGGL(k_out, dim3(BATCH * NQ / 4), dim3(256), 0, stream,
                       head, Wout, bout, out);
}